// Round 2
// baseline (718.613 us; speedup 1.0000x reference)
//
#include <hip/hip_runtime.h>
#include <stdint.h>

#define B_ 2
#define S_ 2048
#define D_ 1024
#define H_ 16
#define DK_ 64
#define DFF_ 4096
#define M_ (B_*S_)   // 4096 rows

typedef __bf16 bf16x8 __attribute__((ext_vector_type(8)));
typedef float  f32x4  __attribute__((ext_vector_type(4)));

union BF8 { bf16x8 v; unsigned short u[8]; unsigned int w[4]; };

__device__ __forceinline__ unsigned short f2bf(float f) {
    union { float f; unsigned int u; } x; x.f = f;
    unsigned int r = x.u + 0x7FFFu + ((x.u >> 16) & 1u);
    return (unsigned short)(r >> 16);
}
__device__ __forceinline__ float bf2f(unsigned short h) {
    union { unsigned int u; float f; } x; x.u = ((unsigned int)h) << 16;
    return x.f;
}

// ---------------- workspace layout (bytes) ----------------
// flags @0 (256B)
static constexpr size_t OFS_XC   = 256;                    // x canonical bf16, 8388608
static constexpr size_t OFS_MASK = OFS_XC   + 8388608;     // mask u8, 8388608
static constexpr size_t OFS_WQKV = OFS_MASK + 8388608;     // Wq|Wk|Wv bf16, 6291456
static constexpr size_t OFS_WO   = OFS_WQKV + 6291456;     // 2097152
static constexpr size_t OFS_W1   = OFS_WO   + 2097152;     // 8388608
static constexpr size_t OFS_W2   = OFS_W1   + 8388608;     // 8388608
static constexpr size_t OFS_BIAS = OFS_W2   + 8388608;     // fp32 biases, 53248
static constexpr size_t OFS_S0   = OFS_BIAS + 53248;       // nx1 -> ctx
static constexpr size_t OFS_S1   = OFS_S0   + 8388608;     // q   -> x2
static constexpr size_t OFS_S2   = OFS_S1   + 8388608;     // k   -> nx2
static constexpr size_t OFS_S3   = OFS_S2   + 8388608;     // v
static constexpr size_t OFS_H    = OFS_S3   + 8388608;     // ffn hidden bf16, 33554432
// total = 109105408 bytes

// bias region sub-offsets (in floats)
#define BOF_QKV 0
#define BOF_O   3072
#define BOF_2   4096
#define BOF_GA  5120
#define BOF_BA  6144
#define BOF_GF  7168
#define BOF_BF  8192
#define BOF_1   9216

// ---------------- dtype detection ----------------
// flags[0]: float mode 0=fp32 1=bf16 2=fp16
// flags[1]: mask mode  0=int32 1=int8 2=fp32 3=u16-nonzero
__global__ void detect_kernel(const unsigned int* __restrict__ g_attn,
                              const unsigned int* __restrict__ mask,
                              int* __restrict__ flags) {
    if (threadIdx.x != 0 || blockIdx.x != 0) return;
    unsigned int w0 = g_attn[0];
    int fm = (w0 == 0x3F800000u) ? 0 : ((w0 == 0x3C003C00u) ? 2 : 1);
    bool a32 = true, a8 = true, af32 = true;
    for (int i = 0; i < 128; i++) {
        unsigned int w = mask[i];
        if (w > 1u) a32 = false;
        if (w != 0u && w != 0x3F800000u) af32 = false;
        for (int j = 0; j < 4; j++) {
            unsigned int bt = (w >> (8*j)) & 0xFFu;
            if (bt > 1u) a8 = false;
        }
    }
    int mm = a32 ? 0 : (a8 ? 1 : (af32 ? 2 : 3));
    flags[0] = fm; flags[1] = mm;
}

// ---------------- canonicalize big float tensors -> bf16 ----------------
struct BigSrc { const void* s[7]; };  // x, Wq, Wk, Wv, Wo, W1, W2

__device__ __forceinline__ void conv4(const void* src, size_t si,
                                      unsigned short* dst, size_t di, int fm) {
    ushort4 ov;
    if (fm == 1) {
        ov = *(const ushort4*)((const unsigned short*)src + si);
    } else if (fm == 0) {
        const float* fp = (const float*)src + si;
        float4 f = *(const float4*)fp;
        ov.x = f2bf(f.x); ov.y = f2bf(f.y); ov.z = f2bf(f.z); ov.w = f2bf(f.w);
    } else {
        const _Float16* hp = (const _Float16*)src + si;
        ov.x = f2bf((float)hp[0]); ov.y = f2bf((float)hp[1]);
        ov.z = f2bf((float)hp[2]); ov.w = f2bf((float)hp[3]);
    }
    *(ushort4*)(dst + di) = ov;
}

__global__ __launch_bounds__(256) void convert_big_kernel(BigSrc srcs, char* ws) {
    const int fm = ((const int*)ws)[0];
    size_t i = ((size_t)blockIdx.x * 256 + threadIdx.x) * 4;
    if (i >= 16777216) return;
    if (i < 4194304) {                       // x
        conv4(srcs.s[0], i, (unsigned short*)(ws + OFS_XC), i, fm);
    } else if (i < 7340032) {                // Wq|Wk|Wv -> contiguous WQKV
        size_t off = i - 4194304;
        int sub = (int)(off >> 20);          // 1048576-element segments
        size_t loc = off & 1048575;
        conv4(srcs.s[1 + sub], loc, (unsigned short*)(ws + OFS_WQKV), off, fm);
    } else if (i < 8388608) {                // Wo
        size_t off = i - 7340032;
        conv4(srcs.s[4], off, (unsigned short*)(ws + OFS_WO), off, fm);
    } else if (i < 12582912) {               // W1
        size_t off = i - 8388608;
        conv4(srcs.s[5], off, (unsigned short*)(ws + OFS_W1), off, fm);
    } else {                                 // W2
        size_t off = i - 12582912;
        conv4(srcs.s[6], off, (unsigned short*)(ws + OFS_W2), off, fm);
    }
}

// ---------------- canonicalize small float tensors -> fp32 ----------------
struct SmallSrc { const void* s[10]; }; // bq,bk,bv,bo,b2,g_attn,b_attn,g_ffn,b_ffn,b1

__global__ __launch_bounds__(256) void convert_small_kernel(SmallSrc srcs, char* ws) {
    int idx = blockIdx.x * 256 + threadIdx.x;
    if (idx >= 13312) return;
    const int fm = ((const int*)ws)[0];
    int seg = idx >> 10; if (seg > 9) seg = 9;
    int loc = idx - seg * 1024;
    const void* s = srcs.s[seg];
    float f;
    if (fm == 1)      f = bf2f(((const unsigned short*)s)[loc]);
    else if (fm == 0) f = ((const float*)s)[loc];
    else              f = (float)((const _Float16*)s)[loc];
    ((float*)(ws + OFS_BIAS))[idx] = f;
}

// ---------------- canonicalize mask -> u8 ----------------
__global__ __launch_bounds__(256) void convert_mask_kernel(const void* msrc, char* ws) {
    size_t i = ((size_t)blockIdx.x * 256 + threadIdx.x) * 4;
    if (i >= 8388608) return;
    const int mm = ((const int*)ws)[1];
    unsigned char o0, o1, o2, o3;
    if (mm == 0) {
        const int* p = (const int*)msrc;
        o0 = p[i] != 0; o1 = p[i+1] != 0; o2 = p[i+2] != 0; o3 = p[i+3] != 0;
    } else if (mm == 1) {
        const unsigned char* p = (const unsigned char*)msrc;
        o0 = p[i] != 0; o1 = p[i+1] != 0; o2 = p[i+2] != 0; o3 = p[i+3] != 0;
    } else if (mm == 2) {
        const unsigned int* p = (const unsigned int*)msrc;
        o0 = p[i] != 0; o1 = p[i+1] != 0; o2 = p[i+2] != 0; o3 = p[i+3] != 0;
    } else {
        const unsigned short* p = (const unsigned short*)msrc;
        o0 = p[i] != 0; o1 = p[i+1] != 0; o2 = p[i+2] != 0; o3 = p[i+3] != 0;
    }
    unsigned char* d = (unsigned char*)(ws + OFS_MASK) + i;
    d[0] = o0; d[1] = o1; d[2] = o2; d[3] = o3;
}

// ---------------- layernorm (one block per row) ----------------
__global__ __launch_bounds__(256) void ln_kernel(const unsigned short* __restrict__ x,
                                                 const float* __restrict__ g,
                                                 const float* __restrict__ b,
                                                 unsigned short* __restrict__ out) {
    const int row = blockIdx.x;
    const int t = threadIdx.x;
    const unsigned short* xr = x + (size_t)row * D_;
    ushort4 xv = *(const ushort4*)(xr + t * 4);
    float f0 = bf2f(xv.x), f1 = bf2f(xv.y), f2 = bf2f(xv.z), f3 = bf2f(xv.w);
    float s = f0 + f1 + f2 + f3;
    float q = f0*f0 + f1*f1 + f2*f2 + f3*f3;
    for (int m = 1; m < 64; m <<= 1) { s += __shfl_xor(s, m); q += __shfl_xor(q, m); }
    __shared__ float red[8];
    __shared__ float mv[2];
    int w = t >> 6, u = t & 63;
    if (u == 0) { red[w*2] = s; red[w*2+1] = q; }
    __syncthreads();
    if (t == 0) {
        float S = red[0] + red[2] + red[4] + red[6];
        float Q = red[1] + red[3] + red[5] + red[7];
        float mu = S * (1.0f / D_);
        float var = Q * (1.0f / D_) - mu * mu;
        mv[0] = mu; mv[1] = rsqrtf(var + 1e-5f);
    }
    __syncthreads();
    float mu = mv[0], r = mv[1];
    int i = t * 4;
    ushort4 ov;
    ov.x = f2bf((f0 - mu) * r * g[i]   + b[i]);
    ov.y = f2bf((f1 - mu) * r * g[i+1] + b[i+1]);
    ov.z = f2bf((f2 - mu) * r * g[i+2] + b[i+2]);
    ov.w = f2bf((f3 - mu) * r * g[i+3] + b[i+3]);
    *(ushort4*)(out + (size_t)row * D_ + i) = ov;
}

// ---------------- GEMM: C = A[MxK] * Bm[NxK]^T (+epilogue) ----------------
// EPI 0: out(bf16) = acc + bias[n] + res[m,n]          (internal residual)
// EPI 1: out(bf16) = gelu_exact(acc + bias[n])
// EPI 2: qkv scatter: n in [0,3072) -> {q,k,v}[b,h,s,dk]
// EPI 3: final: val = acc + bias[n] + res[m,n]; store per flags[0] dtype
template<int EPI>
__global__ __launch_bounds__(256) void gemm_bt_kernel(
    const unsigned short* __restrict__ A,
    const unsigned short* __restrict__ Bm,
    const float* __restrict__ bias,
    const unsigned short* __restrict__ res,
    unsigned short* __restrict__ out,
    unsigned short* __restrict__ q_out,
    unsigned short* __restrict__ k_out,
    unsigned short* __restrict__ v_out,
    const int* __restrict__ flags,
    int M, int N, int K)
{
    __shared__ __attribute__((aligned(16))) unsigned short ldsA[128*32];
    __shared__ __attribute__((aligned(16))) unsigned short ldsB[128*32];
    const int t = threadIdx.x;
    const int w = t >> 6, u = t & 63, quad = u >> 4, l15 = u & 15;
    const int bx = blockIdx.x, by = blockIdx.y;

    int fm = 1;
    if constexpr (EPI == 3) fm = flags[0];

    const int c0 = t, c1 = t + 256;  // chunk c = 16B: row=(c>>6)*16+(c&15), k=((c>>4)&3)*8
    const int ar0 = by*128 + ((c0 >> 6) << 4) + (c0 & 15), ak0 = ((c0 >> 4) & 3) * 8;
    const int ar1 = by*128 + ((c1 >> 6) << 4) + (c1 & 15), ak1 = ((c1 >> 4) & 3) * 8;
    const int br0 = bx*128 + ((c0 >> 6) << 4) + (c0 & 15);
    const int br1 = bx*128 + ((c1 >> 6) << 4) + (c1 & 15);
    const unsigned short* pa0 = A  + (size_t)ar0 * K + ak0;
    const unsigned short* pa1 = A  + (size_t)ar1 * K + ak1;
    const unsigned short* pb0 = Bm + (size_t)br0 * K + ak0;
    const unsigned short* pb1 = Bm + (size_t)br1 * K + ak1;

    f32x4 acc[4][4];
    #pragma unroll
    for (int i = 0; i < 4; i++)
        #pragma unroll
        for (int j = 0; j < 4; j++) acc[i][j] = (f32x4){0.f, 0.f, 0.f, 0.f};

    const int mbase = (w >> 1) * 4;  // 16-row band units
    const int nbase = (w & 1) * 4;

    for (int k0 = 0; k0 < K; k0 += 32) {
        bf16x8 va0 = *(const bf16x8*)pa0;
        bf16x8 va1 = *(const bf16x8*)pa1;
        bf16x8 vb0 = *(const bf16x8*)pb0;
        bf16x8 vb1 = *(const bf16x8*)pb1;
        pa0 += 32; pa1 += 32; pb0 += 32; pb1 += 32;
        __syncthreads();
        *(bf16x8*)&ldsA[c0*8] = va0;
        *(bf16x8*)&ldsA[c1*8] = va1;
        *(bf16x8*)&ldsB[c0*8] = vb0;
        *(bf16x8*)&ldsB[c1*8] = vb1;
        __syncthreads();
        bf16x8 af[4], bfr[4];
        #pragma unroll
        for (int mt = 0; mt < 4; mt++) af[mt]  = *(const bf16x8*)&ldsA[((mbase+mt)*64 + u) * 8];
        #pragma unroll
        for (int nt = 0; nt < 4; nt++) bfr[nt] = *(const bf16x8*)&ldsB[((nbase+nt)*64 + u) * 8];
        #pragma unroll
        for (int mt = 0; mt < 4; mt++)
            #pragma unroll
            for (int nt = 0; nt < 4; nt++)
                acc[mt][nt] = __builtin_amdgcn_mfma_f32_16x16x32_bf16(af[mt], bfr[nt], acc[mt][nt], 0, 0, 0);
    }

    #pragma unroll
    for (int mt = 0; mt < 4; mt++) {
        #pragma unroll
        for (int nt = 0; nt < 4; nt++) {
            #pragma unroll
            for (int r = 0; r < 4; r++) {
                int m = by*128 + (w >> 1)*64 + mt*16 + quad*4 + r;
                int n = bx*128 + (w & 1)*64 + nt*16 + l15;
                float val = acc[mt][nt][r] + bias[n];
                if constexpr (EPI == 0) {
                    val += bf2f(res[(size_t)m * N + n]);
                    out[(size_t)m * N + n] = f2bf(val);
                } else if constexpr (EPI == 1) {
                    float ge = 0.5f * val * (1.0f + erff(val * 0.70710678118654752f));
                    out[(size_t)m * N + n] = f2bf(ge);
                } else if constexpr (EPI == 2) {
                    int sel = n >> 10, nn = n & 1023;
                    int hh = nn >> 6, dk = nn & 63;
                    int bb = m >> 11, ss = m & 2047;
                    unsigned short* dst = sel == 0 ? q_out : (sel == 1 ? k_out : v_out);
                    dst[(((size_t)bb * H_ + hh) * S_ + ss) * DK_ + dk] = f2bf(val);
                } else {
                    val += bf2f(res[(size_t)m * N + n]);
                    size_t idx = (size_t)m * N + n;
                    if (fm == 0)      ((float*)out)[idx] = val;
                    else if (fm == 2) ((_Float16*)out)[idx] = (_Float16)val;
                    else              out[idx] = f2bf(val);
                }
            }
        }
    }
}

// ---------------- flash attention ----------------
// grid (32 qtiles, 16 heads, 2 batch), 256 threads = 4 waves, wave = 16 q rows
__global__ __launch_bounds__(256) void attn_kernel(
    const unsigned short* __restrict__ q,
    const unsigned short* __restrict__ k,
    const unsigned short* __restrict__ v,
    const unsigned char* __restrict__ mask,
    unsigned short* __restrict__ ctx)
{
    const int qt = blockIdx.x, h = blockIdx.y, b = blockIdx.z;
    const int bh = b * H_ + h;
    const int t = threadIdx.x, w = t >> 6, u = t & 63, quad = u >> 4, l15 = u & 15;

    __shared__ __attribute__((aligned(16))) unsigned short Vt[64 * 66];
    __shared__ __attribute__((aligned(16))) unsigned short Pt[4][16 * 66];

    const size_t base = (size_t)bh * S_ * DK_;
    const int qr = qt * 64 + w * 16;

    bf16x8 aq0 = *(const bf16x8*)(q + base + (size_t)(qr + l15) * DK_ + quad * 8);
    bf16x8 aq1 = *(const bf16x8*)(q + base + (size_t)(qr + l15) * DK_ + 32 + quad * 8);

    f32x4 o[4];
    #pragma unroll
    for (int i = 0; i < 4; i++) o[i] = (f32x4){0.f, 0.f, 0.f, 0.f};
    float mrow[4] = {-1e30f, -1e30f, -1e30f, -1e30f};
    float lrow[4] = {0.f, 0.f, 0.f, 0.f};
    const float LOG2E = 1.4426950408889634f;

    for (int kt = 0; kt < S_ / 64; kt++) {
        __syncthreads();
        #pragma unroll
        for (int cc = 0; cc < 2; cc++) {
            int c = t + cc * 256;
            int key = c >> 3, dk0 = (c & 7) * 8;
            BF8 vv;
            vv.v = *(const bf16x8*)(v + base + (size_t)(kt * 64 + key) * DK_ + dk0);
            unsigned int* dst = (unsigned int*)&Vt[key * 66 + dk0];
            dst[0] = vv.w[0]; dst[1] = vv.w[1]; dst[2] = vv.w[2]; dst[3] = vv.w[3];
        }
        __syncthreads();

        f32x4 s[4];
        #pragma unroll
        for (int nt = 0; nt < 4; nt++) s[nt] = (f32x4){0.f, 0.f, 0.f, 0.f};
        #pragma unroll
        for (int nt = 0; nt < 4; nt++) {
            int key = kt * 64 + nt * 16 + l15;
            bf16x8 bk0 = *(const bf16x8*)(k + base + (size_t)key * DK_ + quad * 8);
            bf16x8 bk1 = *(const bf16x8*)(k + base + (size_t)key * DK_ + 32 + quad * 8);
            s[nt] = __builtin_amdgcn_mfma_f32_16x16x32_bf16(aq0, bk0, s[nt], 0, 0, 0);
            s[nt] = __builtin_amdgcn_mfma_f32_16x16x32_bf16(aq1, bk1, s[nt], 0, 0, 0);
        }

        float p[4][4];
        #pragma unroll
        for (int r = 0; r < 4; r++) {
            int qg = qt * 64 + w * 16 + quad * 4 + r;
            const unsigned char* mp = mask + ((size_t)b * S_ + qg) * S_ + kt * 64;
            float rowm = -1e30f;
            #pragma unroll
            for (int nt = 0; nt < 4; nt++) {
                float val = s[nt][r] * 0.125f;
                if (mp[nt * 16 + l15]) val = -10000.0f;
                p[nt][r] = val;
                rowm = fmaxf(rowm, val);
            }
            rowm = fmaxf(rowm, __shfl_xor(rowm, 1));
            rowm = fmaxf(rowm, __shfl_xor(rowm, 2));
            rowm = fmaxf(rowm, __shfl_xor(rowm, 4));
            rowm = fmaxf(rowm, __shfl_xor(rowm, 8));
            float mn = fmaxf(mrow[r], rowm);
            float alpha = exp2f((mrow[r] - mn) * LOG2E);
            mrow[r] = mn;
            float rsum = 0.f;
            #pragma unroll
            for (int nt = 0; nt < 4; nt++) {
                float e = exp2f((p[nt][r] - mn) * LOG2E);
                p[nt][r] = e;
                rsum += e;
            }
            rsum += __shfl_xor(rsum, 1);
            rsum += __shfl_xor(rsum, 2);
            rsum += __shfl_xor(rsum, 4);
            rsum += __shfl_xor(rsum, 8);
            lrow[r] = lrow[r] * alpha + rsum;
            #pragma unroll
            for (int nt = 0; nt < 4; nt++) o[nt][r] *= alpha;
        }

        #pragma unroll
        for (int r = 0; r < 4; r++)
            #pragma unroll
            for (int nt = 0; nt < 4; nt++)
                Pt[w][(quad * 4 + r) * 66 + nt * 16 + l15] = f2bf(p[nt][r]);

        // same-wave LDS RAW: compiler inserts lgkmcnt waits
        #pragma unroll
        for (int ks = 0; ks < 2; ks++) {
            BF8 ap;
            const unsigned int* pw = (const unsigned int*)&Pt[w][0];
            int ub = l15 * 33 + ks * 16 + quad * 4;
            ap.w[0] = pw[ub]; ap.w[1] = pw[ub + 1]; ap.w[2] = pw[ub + 2]; ap.w[3] = pw[ub + 3];
            #pragma unroll
            for (int nt = 0; nt < 4; nt++) {
                BF8 bv;
                #pragma unroll
                for (int j = 0; j < 8; j++)
                    bv.u[j] = Vt[(ks * 32 + quad * 8 + j) * 66 + nt * 16 + l15];
                o[nt] = __builtin_amdgcn_mfma_f32_16x16x32_bf16(ap.v, bv.v, o[nt], 0, 0, 0);
            }
        }
    }

    #pragma unroll
    for (int r = 0; r < 4; r++) {
        float inv = 1.0f / lrow[r];
        int qg = qt * 64 + w * 16 + quad * 4 + r;
        #pragma unroll
        for (int nt = 0; nt < 4; nt++)
            ctx[((size_t)b * S_ + qg) * D_ + h * DK_ + nt * 16 + l15] = f2bf(o[nt][r] * inv);
    }
}

// ---------------- launch ----------------
extern "C" void kernel_launch(void* const* d_in, const int* in_sizes, int n_in,
                              void* d_out, int out_size, void* d_ws, size_t ws_size,
                              hipStream_t stream) {
    char* ws = (char*)d_ws;

    detect_kernel<<<1, 64, 0, stream>>>((const unsigned int*)d_in[14],
                                        (const unsigned int*)d_in[1], (int*)ws);

    BigSrc bs; bs.s[0] = d_in[0]; bs.s[1] = d_in[2]; bs.s[2] = d_in[4];
    bs.s[3] = d_in[6]; bs.s[4] = d_in[8]; bs.s[5] = d_in[10]; bs.s[6] = d_in[12];
    convert_big_kernel<<<16384, 256, 0, stream>>>(bs, ws);

    SmallSrc ss;
    ss.s[0] = d_in[3];  ss.s[1] = d_in[5];  ss.s[2] = d_in[7];  ss.s[3] = d_in[9];
    ss.s[4] = d_in[13]; ss.s[5] = d_in[14]; ss.s[6] = d_in[15]; ss.s[7] = d_in[16];
    ss.s[8] = d_in[17]; ss.s[9] = d_in[11];
    convert_small_kernel<<<52, 256, 0, stream>>>(ss, ws);

    convert_mask_kernel<<<8192, 256, 0, stream>>>(d_in[1], ws);

    const unsigned short* xc  = (const unsigned short*)(ws + OFS_XC);
    const unsigned short* wqk = (const unsigned short*)(ws + OFS_WQKV);
    const unsigned short* wo  = (const unsigned short*)(ws + OFS_WO);
    const unsigned short* w1  = (const unsigned short*)(ws + OFS_W1);
    const unsigned short* w2  = (const unsigned short*)(ws + OFS_W2);
    float* biasf = (float*)(ws + OFS_BIAS);
    unsigned short* nx1 = (unsigned short*)(ws + OFS_S0);
    unsigned short* ctx = (unsigned short*)(ws + OFS_S0);
    unsigned short* qb  = (unsigned short*)(ws + OFS_S1);
    unsigned short* x2  = (unsigned short*)(ws + OFS_S1);
    unsigned short* kb  = (unsigned short*)(ws + OFS_S2);
    unsigned short* nx2 = (unsigned short*)(ws + OFS_S2);
    unsigned short* vb  = (unsigned short*)(ws + OFS_S3);
    unsigned short* hb  = (unsigned short*)(ws + OFS_H);
    const unsigned char* maskc = (const unsigned char*)(ws + OFS_MASK);
    const int* flags = (const int*)ws;

    ln_kernel<<<4096, 256, 0, stream>>>(xc, biasf + BOF_GA, biasf + BOF_BA, nx1);

    gemm_bt_kernel<2><<<dim3(24, 32), 256, 0, stream>>>(
        nx1, wqk, biasf + BOF_QKV, nullptr, nullptr, qb, kb, vb, nullptr, M_, 3072, 1024);

    attn_kernel<<<dim3(32, 16, 2), 256, 0, stream>>>(qb, kb, vb, maskc, ctx);

    gemm_bt_kernel<0><<<dim3(8, 32), 256, 0, stream>>>(
        ctx, wo, biasf + BOF_O, xc, x2, nullptr, nullptr, nullptr, nullptr, M_, 1024, 1024);

    ln_kernel<<<4096, 256, 0, stream>>>(x2, biasf + BOF_GF, biasf + BOF_BF, nx2);

    gemm_bt_kernel<1><<<dim3(32, 32), 256, 0, stream>>>(
        nx2, w1, biasf + BOF_1, nullptr, hb, nullptr, nullptr, nullptr, nullptr, M_, 4096, 1024);

    gemm_bt_kernel<3><<<dim3(8, 32), 256, 0, stream>>>(
        hb, w2, biasf + BOF_2, x2, (unsigned short*)d_out, nullptr, nullptr, nullptr, flags, M_, 1024, 4096);
}